// Round 9
// baseline (298.131 us; speedup 1.0000x reference)
//
#include <hip/hip_runtime.h>

#define NN 100000
#define NE 1600000
#define KB 782      // coarse buckets: ceil(100000/128)
#define BSH 7       // bucket = dst >> 7; 128 nodes per bucket
#define MAXB 4096   // fixed slots per bucket (mean 2046, max ~2250 — safe)
#define PBLK 200    // cpart blocks; NE/PBLK = 8000 edges per block

// Workspace layout in 4-byte units:
#define OFF_CC    0            // 1024: per-bucket edge counts
#define OFF_RST   1024         // 100096: per-node edge-range start (global slot index)
#define OFF_RDG   101120       // 100096: per-node degree
#define OFF_STAGE 201216       // KB*MAXB: node-sorted src indices after sort_kernel
#define OFF_XB    3404288      // x bf16 [100096,128]
#define OFF_XF8   9810432      // x fp8 [100096,128]; pb bf16 [100096,64] aliases (xf8 dead after fgemm1... NOTE: pb written by fgemm1 while xf8 still live -> use separate region)
#define OFF_PB    13013504     // pl bf16 [100096,64]
#define OFF_HB    19419648     // h bf16 [100096,128]
#define OFF_W1LP  25825792     // packed weights bf16
#define OFF_W1RP  (25825792 + 8192)
#define OFF_W2LP  (25825792 + 16384)
#define OFF_W2RP  (25825792 + 20480)

typedef __bf16 bf16x8 __attribute__((ext_vector_type(8)));
typedef float f32x4 __attribute__((ext_vector_type(4)));
typedef float f32x2 __attribute__((ext_vector_type(2)));

static __device__ __forceinline__ ushort f2bf(float f) {
    unsigned u = __float_as_uint(f);
    return (ushort)((u + 0x7fffu + ((u >> 16) & 1u)) >> 16);
}
static __device__ __forceinline__ float bflo(unsigned u) { return __uint_as_float(u << 16); }
static __device__ __forceinline__ float bfhi(unsigned u) { return __uint_as_float(u & 0xffff0000u); }

// ---------------------------------------------------------------------------
// x (fp32) -> xb (bf16, for gemm1) and xf8 (fp8 e4m3, for layer-1 gather).
// ---------------------------------------------------------------------------
__global__ void cvt_kernel(const float* __restrict__ x, ushort* __restrict__ xb,
                           unsigned* __restrict__ xf8) {
    int i = blockIdx.x * 256 + threadIdx.x;  // covers NN*128/4 = 3.2M
    float4 v = ((const float4*)x)[i];
    uint2 o;
    o.x = (unsigned)f2bf(v.x) | ((unsigned)f2bf(v.y) << 16);
    o.y = (unsigned)f2bf(v.z) | ((unsigned)f2bf(v.w) << 16);
    ((uint2*)xb)[i] = o;
    int p8 = __builtin_amdgcn_cvt_pk_fp8_f32(v.x, v.y, 0, false);
    p8 = __builtin_amdgcn_cvt_pk_fp8_f32(v.z, v.w, p8, true);
    xf8[i] = (unsigned)p8;
}

// ---------------------------------------------------------------------------
// Pack all 4 weight matrices fp32 -> bf16 MFMA B-frag layout.
// ---------------------------------------------------------------------------
__global__ void pack_kernel(const float* __restrict__ W1l, const float* __restrict__ W1r,
                            const float* __restrict__ W2l, const float* __restrict__ W2r,
                            ushort* __restrict__ w1lp, ushort* __restrict__ w1rp,
                            ushort* __restrict__ w2lp, ushort* __restrict__ w2rp) {
    int blk = blockIdx.x;
    const float* W;
    ushort* out;
    int N, frag0;
    if (blk < 8)       { W = W1l; out = w1lp; N = 128; frag0 = blk * 4; }
    else if (blk < 16) { W = W1r; out = w1rp; N = 128; frag0 = (blk - 8) * 4; }
    else if (blk < 20) { W = W2l; out = w2lp; N = 64;  frag0 = (blk - 16) * 4; }
    else               { W = W2r; out = w2rp; N = 64;  frag0 = (blk - 20) * 4; }
    int lane = threadIdx.x & 63;
    int frag = frag0 + (threadIdx.x >> 6);
    int NT = N >> 4;
    int ktile = frag / NT, ntile = frag - ktile * NT;
    int k = ktile * 32 + (lane >> 4) * 8;
    int n = ntile * 16 + (lane & 15);
    ushort tmp[8];
#pragma unroll
    for (int j = 0; j < 8; ++j) tmp[j] = f2bf(W[(k + j) * N + n]);
    uint4 o;
    o.x = (unsigned)tmp[0] | ((unsigned)tmp[1] << 16);
    o.y = (unsigned)tmp[2] | ((unsigned)tmp[3] << 16);
    o.z = (unsigned)tmp[4] | ((unsigned)tmp[5] << 16);
    o.w = (unsigned)tmp[6] | ((unsigned)tmp[7] << 16);
    *(uint4*)&out[(frag * 64 + lane) * 8] = o;
}

// ---------------------------------------------------------------------------
// Coarse partition, fixed-capacity slots. Block-level LDS histogram -> one
// global atomicAdd per (block,bucket) -> LDS-cursor placement.
// ---------------------------------------------------------------------------
__global__ __launch_bounds__(1024) void cpart_kernel(const int* __restrict__ src,
                                                     const int* __restrict__ dst,
                                                     int* __restrict__ cc,
                                                     unsigned* __restrict__ stage) {
    __shared__ int hist[KB];
    __shared__ int cur[KB];
    int t = threadIdx.x;
    int e0 = blockIdx.x * (NE / PBLK);
    int e1 = e0 + (NE / PBLK);
    for (int i = t; i < KB; i += 1024) hist[i] = 0;
    __syncthreads();
    for (int e = e0 + t; e < e1; e += 1024)
        atomicAdd(&hist[dst[e] >> BSH], 1);
    __syncthreads();
    for (int i = t; i < KB; i += 1024) {
        int c = hist[i];
        cur[i] = c ? atomicAdd(&cc[i], c) : 0;
    }
    __syncthreads();
    for (int e = e0 + t; e < e1; e += 1024) {
        int d = dst[e];
        int bkt = d >> BSH;
        int p = atomicAdd(&cur[bkt], 1);
        if (p < MAXB)
            stage[bkt * MAXB + p] = ((unsigned)(d & 127) << 17) | (unsigned)src[e];
    }
}

// ---------------------------------------------------------------------------
// Sort: one block per bucket. Build the local CSR in LDS (paid ONCE), write
// the node-sorted src list back into the stage slots in place, and emit
// global rstart/rdeg so the gather phases need no LDS and no CSR build.
// ---------------------------------------------------------------------------
__global__ __launch_bounds__(256) void sort_kernel(unsigned* __restrict__ stage,
                                                   const int* __restrict__ cc,
                                                   int* __restrict__ rstart,
                                                   int* __restrict__ rdeg) {
    __shared__ unsigned ssrc[MAXB];
    __shared__ int sc[128];
    __shared__ int loff[129];
    __shared__ int lcur[128];
    int t = threadIdx.x;
    int b = blockIdx.x;
    unsigned* st = stage + b * MAXB;
    int cnt = min(cc[b], MAXB);

    if (t < 128) lcur[t] = 0;
    __syncthreads();
    for (int i = t; i < cnt; i += 256) atomicAdd(&lcur[st[i] >> 17], 1);
    __syncthreads();
    if (t < 128) sc[t] = lcur[t];
    __syncthreads();
    for (int off = 1; off < 128; off <<= 1) {
        int v = (t < 128 && t >= off) ? sc[t - off] : 0;
        __syncthreads();
        if (t < 128) sc[t] += v;
        __syncthreads();
    }
    if (t < 128) {
        int excl = (t == 0) ? 0 : sc[t - 1];
        loff[t] = excl;
        lcur[t] = excl;
    }
    if (t == 127) loff[128] = sc[127];
    __syncthreads();
    for (int i = t; i < cnt; i += 256) {
        unsigned v = st[i];
        int p = atomicAdd(&lcur[v >> 17], 1);
        ssrc[p] = v & 0x1FFFFu;
    }
    __syncthreads();
    for (int i = t; i < cnt; i += 256) st[i] = ssrc[i];
    int node0 = b << BSH;
    if (t < 128 && node0 + t < NN) {
        rstart[node0 + t] = b * MAXB + loff[t];
        rdeg[node0 + t] = loff[t + 1] - loff[t];
    }
}

// ---------------------------------------------------------------------------
// FUSED GEMM1: phase A gathers fp8 x rows for this block's 64 nodes and
// writes bf16 mean DIRECTLY into the MFMA A-tile in LDS (meanb eliminated).
// Then: h = relu(mean@W1l + x@W1r + b1); hb = bf16(h); pb = bf16(h@W2l).
// ---------------------------------------------------------------------------
__global__ __launch_bounds__(256) void gemm1_kernel(const unsigned* __restrict__ es,
                                                    const int* __restrict__ rstart,
                                                    const int* __restrict__ rdeg,
                                                    const unsigned* __restrict__ xf8,
                                                    const ushort* __restrict__ xb,
                                                    const ushort* __restrict__ w1lp,
                                                    const ushort* __restrict__ w1rp,
                                                    const float* __restrict__ b1,
                                                    const ushort* __restrict__ w2lp,
                                                    ushort* __restrict__ hb,
                                                    ushort* __restrict__ pb) {
    __shared__ ushort As[64 * 136];
    int t = threadIdx.x;
    int node0 = blockIdx.x * 64;
    int w = t >> 6, l = t & 63;
    int lrow = w * 16 + (l & 15);
    int lkq = (l >> 4) * 8;
    int cq = l & 15, rq = (l >> 4) * 4;

    // ---- phase A: gather-mean (fp8), quarter-wave per node, 4 rounds ----
    {
        int l4 = t & 15, grp = t >> 4;
        const uint2* xv = (const uint2*)xf8;  // row = 16 uint2 (128 fp8)
#pragma unroll
        for (int i = 0; i < 4; ++i) {
            int nl = i * 16 + grp;
            int node = node0 + nl;
            float a0 = 0.f, a1 = 0.f, a2 = 0.f, a3 = 0.f;
            float a4 = 0.f, a5 = 0.f, a6 = 0.f, a7 = 0.f;
            float inv = 0.f;
            if (node < NN) {
                int s0 = rstart[node];
                int deg = rdeg[node];
                int e = 0;
                for (; e + 4 <= deg; e += 4) {
                    int q0 = es[s0 + e + 0];
                    int q1 = es[s0 + e + 1];
                    int q2 = es[s0 + e + 2];
                    int q3 = es[s0 + e + 3];
                    uint2 u0 = xv[q0 * 16 + l4];
                    uint2 u1 = xv[q1 * 16 + l4];
                    uint2 u2 = xv[q2 * 16 + l4];
                    uint2 u3 = xv[q3 * 16 + l4];
#pragma unroll
                    for (int j = 0; j < 4; ++j) {
                        unsigned lo = (j == 0) ? u0.x : (j == 1) ? u1.x : (j == 2) ? u2.x : u3.x;
                        unsigned hi = (j == 0) ? u0.y : (j == 1) ? u1.y : (j == 2) ? u2.y : u3.y;
                        f32x2 p0 = __builtin_amdgcn_cvt_pk_f32_fp8(lo, false);
                        f32x2 p1 = __builtin_amdgcn_cvt_pk_f32_fp8(lo, true);
                        f32x2 p2 = __builtin_amdgcn_cvt_pk_f32_fp8(hi, false);
                        f32x2 p3 = __builtin_amdgcn_cvt_pk_f32_fp8(hi, true);
                        a0 += p0.x; a1 += p0.y; a2 += p1.x; a3 += p1.y;
                        a4 += p2.x; a5 += p2.y; a6 += p3.x; a7 += p3.y;
                    }
                }
                for (; e < deg; ++e) {
                    uint2 u = xv[es[s0 + e] * 16 + l4];
                    f32x2 p0 = __builtin_amdgcn_cvt_pk_f32_fp8(u.x, false);
                    f32x2 p1 = __builtin_amdgcn_cvt_pk_f32_fp8(u.x, true);
                    f32x2 p2 = __builtin_amdgcn_cvt_pk_f32_fp8(u.y, false);
                    f32x2 p3 = __builtin_amdgcn_cvt_pk_f32_fp8(u.y, true);
                    a0 += p0.x; a1 += p0.y; a2 += p1.x; a3 += p1.y;
                    a4 += p2.x; a5 += p2.y; a6 += p3.x; a7 += p3.y;
                }
                inv = 1.0f / fmaxf((float)deg, 1.0f);
            }
            uint4 o;
            o.x = (unsigned)f2bf(a0 * inv) | ((unsigned)f2bf(a1 * inv) << 16);
            o.y = (unsigned)f2bf(a2 * inv) | ((unsigned)f2bf(a3 * inv) << 16);
            o.z = (unsigned)f2bf(a4 * inv) | ((unsigned)f2bf(a5 * inv) << 16);
            o.w = (unsigned)f2bf(a6 * inv) | ((unsigned)f2bf(a7 * inv) << 16);
            *(uint4*)&As[nl * 136 + 8 * l4] = o;
        }
    }
    __syncthreads();

    f32x4 acc[8];
#pragma unroll
    for (int i = 0; i < 8; ++i) acc[i] = (f32x4){0.f, 0.f, 0.f, 0.f};

    // ---- phase 1: mean @ W1l (A-tile already in LDS) ----
#pragma unroll
    for (int kt = 0; kt < 4; ++kt) {
        bf16x8 a = *(const bf16x8*)&As[lrow * 136 + kt * 32 + lkq];
        const bf16x8* bp = (const bf16x8*)w1lp + (kt * 8) * 64 + l;
#pragma unroll
        for (int nt = 0; nt < 8; ++nt)
            acc[nt] = __builtin_amdgcn_mfma_f32_16x16x32_bf16(a, bp[nt * 64], acc[nt], 0, 0, 0);
    }
    __syncthreads();

    // ---- phase 2: x @ W1r ----
    {
        const uint4* g = (const uint4*)(xb + (size_t)node0 * 128);
#pragma unroll
        for (int i = 0; i < 4; ++i) {
            int chunk = t + 256 * i;
            *(uint4*)&As[(chunk >> 4) * 136 + (chunk & 15) * 8] = g[chunk];
        }
    }
    __syncthreads();
#pragma unroll
    for (int kt = 0; kt < 4; ++kt) {
        bf16x8 a = *(const bf16x8*)&As[lrow * 136 + kt * 32 + lkq];
        const bf16x8* bp = (const bf16x8*)w1rp + (kt * 8) * 64 + l;
#pragma unroll
        for (int nt = 0; nt < 8; ++nt)
            acc[nt] = __builtin_amdgcn_mfma_f32_16x16x32_bf16(a, bp[nt * 64], acc[nt], 0, 0, 0);
    }
    __syncthreads();

    // ---- epilogue: relu + bias, park h (bf16) in LDS ----
#pragma unroll
    for (int nt = 0; nt < 8; ++nt) {
        int n = nt * 16 + cq;
        float bias = b1[n];
#pragma unroll
        for (int r = 0; r < 4; ++r) {
            float hv = fmaxf(acc[nt][r] + bias, 0.0f);
            As[(w * 16 + rq + r) * 136 + n] = f2bf(hv);
        }
    }
    __syncthreads();

    // ---- stream hb out (coalesced) ----
    {
        uint4* g = (uint4*)(hb + (size_t)node0 * 128);
#pragma unroll
        for (int i = 0; i < 4; ++i) {
            int chunk = t + 256 * i;
            if (node0 + (chunk >> 4) < NN)
                g[chunk] = *(const uint4*)&As[(chunk >> 4) * 136 + (chunk & 15) * 8];
        }
    }

    // ---- pl = h @ W2l ----
    f32x4 acc2[4];
#pragma unroll
    for (int i = 0; i < 4; ++i) acc2[i] = (f32x4){0.f, 0.f, 0.f, 0.f};
#pragma unroll
    for (int kt = 0; kt < 4; ++kt) {
        bf16x8 a = *(const bf16x8*)&As[lrow * 136 + kt * 32 + lkq];
        const bf16x8* bp = (const bf16x8*)w2lp + (kt * 4) * 64 + l;
#pragma unroll
        for (int nt = 0; nt < 4; ++nt)
            acc2[nt] = __builtin_amdgcn_mfma_f32_16x16x32_bf16(a, bp[nt * 64], acc2[nt], 0, 0, 0);
    }
    __syncthreads();

    // ---- park pb (bf16) in LDS, stream out coalesced ----
#pragma unroll
    for (int nt = 0; nt < 4; ++nt)
#pragma unroll
        for (int r = 0; r < 4; ++r)
            As[(w * 16 + rq + r) * 136 + nt * 16 + cq] = f2bf(acc2[nt][r]);
    __syncthreads();
    {
        uint4* g = (uint4*)(pb + (size_t)node0 * 64);
#pragma unroll
        for (int i = 0; i < 2; ++i) {
            int chunk = t + 256 * i;
            if (node0 + (chunk >> 3) < NN)
                g[chunk] = *(const uint4*)&As[(chunk >> 3) * 136 + (chunk & 7) * 8];
        }
    }
}

// ---------------------------------------------------------------------------
// FUSED GEMM2: phase A gathers bf16 pl rows for this block's 64 nodes into an
// 8KB LDS mean tile (packed bf16; meanp eliminated). Then
// out = mean2 + hb@W2r + b2.
// ---------------------------------------------------------------------------
__global__ __launch_bounds__(256) void gemm2_kernel(const unsigned* __restrict__ es,
                                                    const int* __restrict__ rstart,
                                                    const int* __restrict__ rdeg,
                                                    const ushort* __restrict__ pbt,
                                                    const ushort* __restrict__ hb,
                                                    const ushort* __restrict__ w2rp,
                                                    const float* __restrict__ b2,
                                                    float* __restrict__ out) {
    __shared__ ushort As[64 * 136];
    __shared__ unsigned ms[64 * 32];  // mean2 as packed bf16x2, row-major [node][ch/2]
    int t = threadIdx.x;
    int node0 = blockIdx.x * 64;
    int w = t >> 6, l = t & 63;
    int lrow = w * 16 + (l & 15);
    int lkq = (l >> 4) * 8;
    int cq = l & 15, rq = (l >> 4) * 4;

    // ---- phase A: gather-mean over pl (bf16), half-wave per node, 8 rounds ----
    {
        int l5 = t & 31, hw = t >> 5;
        const unsigned* pbu = (const unsigned*)pbt;  // row = 32 uint (64 bf16)
#pragma unroll
        for (int i = 0; i < 8; ++i) {
            int nl = i * 8 + hw;
            int node = node0 + nl;
            float a0 = 0.f, a1 = 0.f;
            float inv = 0.f;
            if (node < NN) {
                int s0 = rstart[node];
                int deg = rdeg[node];
                int e = 0;
                for (; e + 4 <= deg; e += 4) {
                    unsigned u0 = pbu[es[s0 + e + 0] * 32 + l5];
                    unsigned u1 = pbu[es[s0 + e + 1] * 32 + l5];
                    unsigned u2 = pbu[es[s0 + e + 2] * 32 + l5];
                    unsigned u3 = pbu[es[s0 + e + 3] * 32 + l5];
                    a0 += bflo(u0) + bflo(u1) + bflo(u2) + bflo(u3);
                    a1 += bfhi(u0) + bfhi(u1) + bfhi(u2) + bfhi(u3);
                }
                for (; e < deg; ++e) {
                    unsigned u = pbu[es[s0 + e] * 32 + l5];
                    a0 += bflo(u); a1 += bfhi(u);
                }
                inv = 1.0f / fmaxf((float)deg, 1.0f);
            }
            ms[nl * 32 + l5] = (unsigned)f2bf(a0 * inv) | ((unsigned)f2bf(a1 * inv) << 16);
        }
    }

    // ---- load hb tile ----
    {
        const uint4* g = (const uint4*)(hb + (size_t)node0 * 128);
#pragma unroll
        for (int i = 0; i < 4; ++i) {
            int chunk = t + 256 * i;
            *(uint4*)&As[(chunk >> 4) * 136 + (chunk & 15) * 8] = g[chunk];
        }
    }
    __syncthreads();

    f32x4 acc[4];
#pragma unroll
    for (int i = 0; i < 4; ++i) acc[i] = (f32x4){0.f, 0.f, 0.f, 0.f};
#pragma unroll
    for (int kt = 0; kt < 4; ++kt) {
        bf16x8 a = *(const bf16x8*)&As[lrow * 136 + kt * 32 + lkq];
        const bf16x8* bp = (const bf16x8*)w2rp + (kt * 4) * 64 + l;
#pragma unroll
        for (int nt = 0; nt < 4; ++nt)
            acc[nt] = __builtin_amdgcn_mfma_f32_16x16x32_bf16(a, bp[nt * 64], acc[nt], 0, 0, 0);
    }

#pragma unroll
    for (int nt = 0; nt < 4; ++nt) {
        int n = nt * 16 + cq;
        float bias = b2[n];
#pragma unroll
        for (int r = 0; r < 4; ++r) {
            int row = node0 + w * 16 + rq + r;
            if (row < NN) {
                unsigned u = ms[(w * 16 + rq + r) * 32 + (n >> 1)];
                float m = (n & 1) ? bfhi(u) : bflo(u);
                out[(size_t)row * 64 + n] = acc[nt][r] + bias + m;
            }
        }
    }
}

extern "C" void kernel_launch(void* const* d_in, const int* in_sizes, int n_in,
                              void* d_out, int out_size, void* d_ws, size_t ws_size,
                              hipStream_t stream) {
    const float* x   = (const float*)d_in[0];
    const int*   ei  = (const int*)d_in[1];
    const float* W1l = (const float*)d_in[2];
    const float* W1r = (const float*)d_in[3];
    const float* b1  = (const float*)d_in[4];
    const float* W2l = (const float*)d_in[5];
    const float* W2r = (const float*)d_in[6];
    const float* b2  = (const float*)d_in[7];

    const int* src = ei;
    const int* dst = ei + NE;

    int*      ws_i   = (int*)d_ws;
    int*      cc     = ws_i + OFF_CC;
    int*      rstart = ws_i + OFF_RST;
    int*      rdeg   = ws_i + OFF_RDG;
    unsigned* stage  = (unsigned*)(ws_i + OFF_STAGE);
    ushort*   xb     = (ushort*)(ws_i + OFF_XB);
    unsigned* xf8    = (unsigned*)(ws_i + OFF_XF8);
    ushort*   pb     = (ushort*)(ws_i + OFF_PB);
    ushort*   hb     = (ushort*)(ws_i + OFF_HB);
    ushort*   w1lp   = (ushort*)(ws_i + OFF_W1LP);
    ushort*   w1rp   = (ushort*)(ws_i + OFF_W1RP);
    ushort*   w2lp   = (ushort*)(ws_i + OFF_W2LP);
    ushort*   w2rp   = (ushort*)(ws_i + OFF_W2RP);

    // Prep: zero cursors, convert x (bf16+fp8), pack weights, partition, sort.
    hipMemsetAsync(cc, 0, 1024 * sizeof(int), stream);
    cvt_kernel<<<12500, 256, 0, stream>>>(x, xb, xf8);
    pack_kernel<<<24, 256, 0, stream>>>(W1l, W1r, W2l, W2r, w1lp, w1rp, w2lp, w2rp);
    cpart_kernel<<<PBLK, 1024, 0, stream>>>(src, dst, cc, stage);
    sort_kernel<<<KB, 256, 0, stream>>>(stage, cc, rstart, rdeg);

    // Layer 1 (gather fused into GEMM)
    gemm1_kernel<<<(NN + 63) / 64, 256, 0, stream>>>(stage, rstart, rdeg, xf8, xb,
                                                     w1lp, w1rp, b1, w2lp, hb, pb);

    // Layer 2 (gather fused into GEMM; aggregation commuted past W2l)
    gemm2_kernel<<<(NN + 63) / 64, 256, 0, stream>>>(stage, rstart, rdeg, pb, hb,
                                                     w2rp, b2, (float*)d_out);
}